// Round 4
// baseline (218.860 us; speedup 1.0000x reference)
//
#include <hip/hip_runtime.h>

// SpikingLayer: T=64 sequential steps over [B=32, F=16384] fp32 state.
//   state = (x + state) - act
//   state = max(state + 1.0f, 0.0f) - 1.0f   // bit-exact relu(s+1)-1, NOT max(s,-1)
//   act   = state > 0 ? floor(state) : 0
// 134 MB in + 134 MB out => 42.7 us floor at 6.29 TB/s measured copy ceiling.
// Harness also runs 2x ~80us 536MB write-only fills inside the timed region
// (~160us fixed, 6.76 TB/s — not controllable from the kernel).
//
// History (kernel-only estimates; total = kernel + ~160us fills; noise ±3us):
// R2: float4, depth-2, 8 waves/CU   -> ~71 us
// R3: scalar, depth-8, 32 waves/CU  -> ~82 us
// R6: float4, depth-8 ring, NT both -> ~57 us (total 217.4)
// R7: float4, 8-step phase bursts   -> ~54 us (total 215.4) burst shaping ~neutral
// R8: float2, 16 waves/CU           -> ~62 us (total 221.0) regressed
// R9: regular stores (NT ablation)  -> ~57 us (total 218.0) neutral; cache policy falsified
// R10 (this): per-wave ILP. The R3/R8/R7 trend read along "bytes in flight per
// wave" is monotone: 32w x 2KB = 82us, 16w x 4KB = 62us, 8w x 8KB = 54us.
// Width caps at 16 B/lane; continue the axis with TWO independent float4
// chains per thread (i, i+65536): 16 loads in flight/wave, 4 waves/CU.
// A waitcnt on chain A never blocks chain B's issue -> per-wave issue gaps
// (the recurrence's only structural difference from a pure copy) are covered
// by intra-wave ILP. If neutral/regressed, every distinct lever is falsified
// and the kernel is at its mixed-stream wall -> declare roofline.

#define T_STEPS 64
#define NCHAINS (32 * 16384)       // B*F = 524288 independent chains
#define NCHAINS4 (NCHAINS / 4)     // float4 groups: 131072
#define NTHREADS (NCHAINS4 / 2)    // 2 chains per thread: 65536 threads
#define GROUP 8                    // steps per phase (8 x 16 B = 8 KB per chain burst)

typedef float vfloat4 __attribute__((ext_vector_type(4)));

// All macro indices are literal constants after expansion -> everything stays in
// registers (runtime-indexed ext_vector arrays would go to scratch).

#define LOAD_GROUP(BUF, G, IDX)                                                 \
  {                                                                             \
    _Pragma("unroll")                                                           \
    for (int j = 0; j < GROUP; ++j)                                             \
      BUF[j] = __builtin_nontemporal_load(&in[((G) * GROUP + j) * NCHAINS4 + (IDX)]); \
  }

#define STEP_GROUP(BUF, G, S, A, IDX)                                           \
  {                                                                             \
    vfloat4 ov[GROUP];                                                          \
    _Pragma("unroll")                                                           \
    for (int j = 0; j < GROUP; ++j) {                                           \
      vfloat4 x = BUF[j];                                                       \
      float xe[4] = {x.x, x.y, x.z, x.w};                                       \
      _Pragma("unroll")                                                         \
      for (int e = 0; e < 4; ++e) {                                             \
        /* EXACT ref op order: s = (x + s) - a; s = max(s+1,0)-1; a = spikes */ \
        float sv = (xe[e] + S[e]) - A[e];                                       \
        sv = fmaxf(sv + 1.0f, 0.0f) - 1.0f;                                     \
        S[e] = sv;                                                              \
        A[e] = (sv > 0.0f) ? floorf(sv) : 0.0f;                                 \
      }                                                                         \
      vfloat4 av = {A[0], A[1], A[2], A[3]};                                    \
      ov[j] = av;                                                               \
    }                                                                           \
    _Pragma("unroll")                                                           \
    for (int j = 0; j < GROUP; ++j)                                             \
      __builtin_nontemporal_store(ov[j], &out[((G) * GROUP + j) * NCHAINS4 + (IDX)]); \
  }

__global__ __launch_bounds__(256) void spiking_kernel(
    const vfloat4* __restrict__ in, vfloat4* __restrict__ out) {
    const int i  = blockIdx.x * blockDim.x + threadIdx.x;   // chain A
    const int i2 = i + NTHREADS;                            // chain B

    float sA[4] = {0.f, 0.f, 0.f, 0.f};
    float aA[4] = {0.f, 0.f, 0.f, 0.f};
    float sB[4] = {0.f, 0.f, 0.f, 0.f};
    float aB[4] = {0.f, 0.f, 0.f, 0.f};

    vfloat4 xaA[GROUP], xbA[GROUP];   // chain A double buffer
    vfloat4 xaB[GROUP], xbB[GROUP];   // chain B double buffer

    // Prologue: groups 0 and 1 for BOTH chains in flight (32 loads, 32 KB/wave).
    LOAD_GROUP(xaA, 0, i);
    LOAD_GROUP(xaB, 0, i2);
    LOAD_GROUP(xbA, 1, i);
    LOAD_GROUP(xbB, 1, i2);

    // Steady state: compute+store group g (both chains), issue loads for g+2.
    STEP_GROUP(xaA, 0, sA, aA, i);
    STEP_GROUP(xaB, 0, sB, aB, i2);
    LOAD_GROUP(xaA, 2, i);
    LOAD_GROUP(xaB, 2, i2);
    STEP_GROUP(xbA, 1, sA, aA, i);
    STEP_GROUP(xbB, 1, sB, aB, i2);
    LOAD_GROUP(xbA, 3, i);
    LOAD_GROUP(xbB, 3, i2);
    STEP_GROUP(xaA, 2, sA, aA, i);
    STEP_GROUP(xaB, 2, sB, aB, i2);
    LOAD_GROUP(xaA, 4, i);
    LOAD_GROUP(xaB, 4, i2);
    STEP_GROUP(xbA, 3, sA, aA, i);
    STEP_GROUP(xbB, 3, sB, aB, i2);
    LOAD_GROUP(xbA, 5, i);
    LOAD_GROUP(xbB, 5, i2);
    STEP_GROUP(xaA, 4, sA, aA, i);
    STEP_GROUP(xaB, 4, sB, aB, i2);
    LOAD_GROUP(xaA, 6, i);
    LOAD_GROUP(xaB, 6, i2);
    STEP_GROUP(xbA, 5, sA, aA, i);
    STEP_GROUP(xbB, 5, sB, aB, i2);
    LOAD_GROUP(xbA, 7, i);
    LOAD_GROUP(xbB, 7, i2);
    STEP_GROUP(xaA, 6, sA, aA, i);
    STEP_GROUP(xaB, 6, sB, aB, i2);
    STEP_GROUP(xbA, 7, sA, aA, i);
    STEP_GROUP(xbB, 7, sB, aB, i2);
}

extern "C" void kernel_launch(void* const* d_in, const int* in_sizes, int n_in,
                              void* d_out, int out_size, void* d_ws, size_t ws_size,
                              hipStream_t stream) {
    const vfloat4* in = (const vfloat4*)d_in[0];
    vfloat4* out = (vfloat4*)d_out;
    // 65536 threads / 256 = 256 blocks -> 1 block/CU, 4 waves/CU (1/SIMD),
    // 2 independent float4 chains per thread (32 KB in flight per wave).
    spiking_kernel<<<NTHREADS / 256, 256, 0, stream>>>(in, out);
}

// Round 5
// 217.491 us; speedup vs baseline: 1.0063x; 1.0063x over previous
//
#include <hip/hip_runtime.h>

// SpikingLayer: T=64 sequential steps over [B=32, F=16384] fp32 state.
//   state = (x + state) - act
//   state = max(state + 1.0f, 0.0f) - 1.0f   // bit-exact relu(s+1)-1, NOT max(s,-1)
//   act   = state > 0 ? floor(state) : 0
// 134 MB in + 134 MB out => 42.7 us floor at 6.29 TB/s measured copy ceiling.
// Harness also runs 2x ~80us 536MB write-only fills inside the timed region
// (~160us fixed, 6.76 TB/s — not controllable from the kernel).
//
// FINAL: R7 structure (best measured, total 215.4us). Falsification matrix:
//   width 4/8/16 B/lane (R3/R8/R7): 16B wins, capped by ISA
//   occupancy 4..32 waves/CU (R3/R8/R10): neutral-to-regressive beyond 8
//   per-wave ILP, 2 indep chains (R10): neutral
//   burst shaping / direction grouping (R7): neutral
//   NT vs L2-allocating stores (R9): neutral
// Kernel sits at ~54+-3us (~5 TB/s) vs 42.7us copy floor; the residual is
// mixed-R/W HBM efficiency + harness gaps, not kernel-addressable. ROOFLINE.

#define T_STEPS 64
#define NCHAINS (32 * 16384)       // B*F = 524288 independent chains
#define NCHAINS4 (NCHAINS / 4)     // float4 groups: 131072 threads
#define GROUP 8                    // steps per phase (8 x 16 B = 8 KB/wave bursts)

typedef float vfloat4 __attribute__((ext_vector_type(4)));

// All macro indices are literal constants after expansion -> everything stays in
// registers (runtime-indexed ext_vector arrays would go to scratch).

#define LOAD_GROUP(BUF, G)                                                      \
  {                                                                             \
    _Pragma("unroll")                                                           \
    for (int j = 0; j < GROUP; ++j)                                             \
      BUF[j] = __builtin_nontemporal_load(&in[((G) * GROUP + j) * NCHAINS4 + i]); \
  }

#define STEP_GROUP(BUF, G)                                                      \
  {                                                                             \
    vfloat4 ov[GROUP];                                                          \
    _Pragma("unroll")                                                           \
    for (int j = 0; j < GROUP; ++j) {                                           \
      vfloat4 x = BUF[j];                                                       \
      float xe[4] = {x.x, x.y, x.z, x.w};                                       \
      _Pragma("unroll")                                                         \
      for (int e = 0; e < 4; ++e) {                                             \
        /* EXACT ref op order: s = (x + s) - a; s = max(s+1,0)-1; a = spikes */ \
        float sv = (xe[e] + s[e]) - a[e];                                       \
        sv = fmaxf(sv + 1.0f, 0.0f) - 1.0f;                                     \
        s[e] = sv;                                                               \
        a[e] = (sv > 0.0f) ? floorf(sv) : 0.0f;                                 \
      }                                                                         \
      vfloat4 av = {a[0], a[1], a[2], a[3]};                                    \
      ov[j] = av;                                                               \
    }                                                                           \
    _Pragma("unroll")                                                           \
    for (int j = 0; j < GROUP; ++j)                                             \
      __builtin_nontemporal_store(ov[j], &out[((G) * GROUP + j) * NCHAINS4 + i]); \
  }

__global__ __launch_bounds__(256) void spiking_kernel(
    const vfloat4* __restrict__ in, vfloat4* __restrict__ out) {
    const int i = blockIdx.x * blockDim.x + threadIdx.x;

    float s[4] = {0.f, 0.f, 0.f, 0.f};
    float a[4] = {0.f, 0.f, 0.f, 0.f};

    vfloat4 xa[GROUP], xb[GROUP];

    // Prologue: groups 0 and 1 in flight (16 loads, 16 KB/wave) before any compute.
    LOAD_GROUP(xa, 0);
    LOAD_GROUP(xb, 1);

    // Steady state: issue loads for g+1, then compute+store g.
    STEP_GROUP(xa, 0);
    LOAD_GROUP(xa, 2);
    STEP_GROUP(xb, 1);
    LOAD_GROUP(xb, 3);
    STEP_GROUP(xa, 2);
    LOAD_GROUP(xa, 4);
    STEP_GROUP(xb, 3);
    LOAD_GROUP(xb, 5);
    STEP_GROUP(xa, 4);
    LOAD_GROUP(xa, 6);
    STEP_GROUP(xb, 5);
    LOAD_GROUP(xb, 7);
    STEP_GROUP(xa, 6);
    STEP_GROUP(xb, 7);
}

extern "C" void kernel_launch(void* const* d_in, const int* in_sizes, int n_in,
                              void* d_out, int out_size, void* d_ws, size_t ws_size,
                              hipStream_t stream) {
    const vfloat4* in = (const vfloat4*)d_in[0];
    vfloat4* out = (vfloat4*)d_out;
    // 131072 threads / 256 = 512 blocks -> 2 blocks/CU, 8 waves/CU (structural cap:
    // each float4 chain is serial over T; 16 B/lane is the max vmem width)
    spiking_kernel<<<NCHAINS4 / 256, 256, 0, stream>>>(in, out);
}